// Round 8
// baseline (642.322 us; speedup 1.0000x reference)
//
#include <hip/hip_runtime.h>
#include <math.h>

// Problem constants
#define M_TOKENS 16384               // B*S = 4*4096
#define E_EXPERTS 64
#define K_DIM 2048
#define KSPLIT 4
#define KCHUNK (K_DIM / KSPLIT)      // 512
#define PSTRIDE (KSPLIT * E_EXPERTS) // 256 floats per token in partials
#define TT 128                       // tokens per block tile
#define SK 32                        // k-depth per LDS stage
#define NS (KCHUNK / SK)             // 16 stages
#define XPAD 132                     // 128 + 4: keeps 16B alignment, spreads
                                     // transpose-write banks (4-way max)

// ---------------------------------------------------------------------------
// Gates kernel — outer-product GEMM tile, BOTH operands in LDS.
// Fixes the two measured serializers of the r3 family:
//  (1) x 64-line-per-instruction gathers -> coalesced staging + transposed
//      LDS tile, per-lane ds_read_b128 (16 lines/instr on the global side).
//  (2) W SMEM drains (unordered s_load returns forced lgkmcnt(0) per FMA
//      burst) -> W staged in LDS, read per-lane-distributed (no SMEM data
//      stream in the inner loop at all; homogeneous in-order ds stream).
// Wave tile: 32 tokens x 64 experts. Lane (r=lane&7, c=lane>>3) owns
// 4 tokens x 8 experts = 32 acc. Per 2-k step: 6 ds_read_b128 + 64 FMAs.
// Bank checks: A-read banks 4(k+r)..+3 distinct, c-broadcast free; B-read
// 2-way (free); x-transpose writes 4-way (XPAD=132); W writes contiguous.
// Double-buffered, ONE barrier/stage; stage loads issued at stage top and
// pinned with sched_barrier(0) so LLVM cannot sink them (r7 failure mode).
// Accumulation: per (t,e) a single k-ascending FMA chain per 512-chunk,
// KSPLIT=4, reduce order unchanged -> bit-identical to rounds 1/3 (absmax 0).
// ---------------------------------------------------------------------------
__global__ __launch_bounds__(256, 2) void gates_kernel(
    const float* __restrict__ x, const float* __restrict__ W,
    float* __restrict__ part) {
  __shared__ float xT[2][SK][XPAD];     // 33 KB
  __shared__ float wS[2][SK][E_EXPERTS];// 16 KB  (total ~49 KB -> 2 blocks/CU)

  const int tid = threadIdx.x;
  const int lane = tid & 63;
  const int w = tid >> 6;              // wave 0..3 (token quarter)
  const int r = lane & 7;              // token sub-row
  const int c = lane >> 3;             // expert sub-col
  const int tg = blockIdx.x >> 2;
  const int kc = blockIdx.x & 3;
  const int tok0 = tg * TT;
  const int kbase = kc * KCHUNK;

  const int stok = tid >> 3;           // staging token base (0..31), +32*j
  const int sc4 = tid & 7;             // staging k-quad within stage

  float acc[4][8];
#pragma unroll
  for (int i = 0; i < 4; ++i)
#pragma unroll
    for (int j = 0; j < 8; ++j) acc[i][j] = 0.0f;

  float4 stg[4];                       // x stage regs
  float4 wstg[2];                      // W stage regs

#define XLOAD(s)                                                              \
  do {                                                                        \
    const float* xsrc = x + (size_t)tok0 * K_DIM + kbase + (s) * SK + sc4 * 4;\
    _Pragma("unroll") for (int j = 0; j < 4; ++j)                             \
        stg[j] = *reinterpret_cast<const float4*>(                            \
            xsrc + (size_t)(stok + 32 * j) * K_DIM);                          \
  } while (0)

#define WLOAD(s)                                                              \
  do {                                                                        \
    const float* wsrc = W + (size_t)(kbase + (s) * SK) * E_EXPERTS;           \
    wstg[0] = *reinterpret_cast<const float4*>(wsrc + tid * 4);               \
    wstg[1] = *reinterpret_cast<const float4*>(wsrc + (tid + 256) * 4);       \
  } while (0)

#define XWRITE(b)                                                             \
  do {                                                                        \
    _Pragma("unroll") for (int j = 0; j < 4; ++j) {                           \
      int tokj = stok + 32 * j;                                               \
      xT[b][sc4 * 4 + 0][tokj] = stg[j].x;                                    \
      xT[b][sc4 * 4 + 1][tokj] = stg[j].y;                                    \
      xT[b][sc4 * 4 + 2][tokj] = stg[j].z;                                    \
      xT[b][sc4 * 4 + 3][tokj] = stg[j].w;                                    \
    }                                                                         \
  } while (0)

#define WWRITE(b)                                                             \
  do {                                                                        \
    *reinterpret_cast<float4*>(&wS[b][tid >> 4][(tid & 15) * 4]) = wstg[0];   \
    *reinterpret_cast<float4*>(&wS[b][(tid + 256) >> 4][(tid & 15) * 4]) =    \
        wstg[1];                                                              \
  } while (0)

  // prologue: fill buffer 0
  XLOAD(0);
  WLOAD(0);
  XWRITE(0);
  WWRITE(0);
  __syncthreads();

  const int colA = w * 32 + r * 4;     // A-frag column base in xT
  const int colB = c * 8;              // B-frag column base in wS

  for (int s = 0; s < NS; ++s) {
    const int cur = s & 1;
    if (s + 1 < NS) {
      XLOAD(s + 1);                    // issue early; pin placement
      WLOAD(s + 1);
      __builtin_amdgcn_sched_barrier(0);
    }

#pragma unroll
    for (int st = 0; st < SK / 2; ++st) {
      const int k0 = 2 * st;
      float4 a0 = *reinterpret_cast<const float4*>(&xT[cur][k0][colA]);
      float4 a1 = *reinterpret_cast<const float4*>(&xT[cur][k0 + 1][colA]);
      float4 b00 = *reinterpret_cast<const float4*>(&wS[cur][k0][colB]);
      float4 b01 = *reinterpret_cast<const float4*>(&wS[cur][k0][colB + 4]);
      float4 b10 = *reinterpret_cast<const float4*>(&wS[cur][k0 + 1][colB]);
      float4 b11 = *reinterpret_cast<const float4*>(&wS[cur][k0 + 1][colB + 4]);
      float av0[4] = {a0.x, a0.y, a0.z, a0.w};
      float av1[4] = {a1.x, a1.y, a1.z, a1.w};
      float bv0[8] = {b00.x, b00.y, b00.z, b00.w, b01.x, b01.y, b01.z, b01.w};
      float bv1[8] = {b10.x, b10.y, b10.z, b10.w, b11.x, b11.y, b11.z, b11.w};
#pragma unroll
      for (int i = 0; i < 4; ++i)
#pragma unroll
        for (int j = 0; j < 8; ++j)
          acc[i][j] = fmaf(av0[i], bv0[j], acc[i][j]);   // k = 2st
#pragma unroll
      for (int i = 0; i < 4; ++i)
#pragma unroll
        for (int j = 0; j < 8; ++j)
          acc[i][j] = fmaf(av1[i], bv1[j], acc[i][j]);   // k = 2st+1
    }

    if (s + 1 < NS) {
      const int nxt = (s + 1) & 1;
      XWRITE(nxt);
      WWRITE(nxt);
      __syncthreads();
    }
  }
#undef XLOAD
#undef WLOAD
#undef XWRITE
#undef WWRITE

  // epilogue: per owned token, 8 contiguous floats -> 2 float4 stores
#pragma unroll
  for (int i = 0; i < 4; ++i) {
    const int t = tok0 + w * 32 + r * 4 + i;
    float* p = part + (size_t)t * PSTRIDE + kc * E_EXPERTS + colB;
    *reinterpret_cast<float4*>(p) =
        make_float4(acc[i][0], acc[i][1], acc[i][2], acc[i][3]);
    *reinterpret_cast<float4*>(p + 4) =
        make_float4(acc[i][4], acc[i][5], acc[i][6], acc[i][7]);
  }
}

// ---------------------------------------------------------------------------
// Reduce + bias + top-2 + softmax (unchanged from round 3 — passed exact).
// ---------------------------------------------------------------------------
__global__ __launch_bounds__(64) void reduce_topk_kernel(
    const float* __restrict__ part, const float* __restrict__ bias,
    float* __restrict__ out) {
  const int t = blockIdx.x * 64 + threadIdx.x;
  const float4* p = reinterpret_cast<const float4*>(part + (size_t)t * PSTRIDE);
  const float4* b4 = reinterpret_cast<const float4*>(bias);

  float m1 = -INFINITY, m2 = -INFINITY;
  int i1 = 0, i2 = 0;

#pragma unroll 4
  for (int e4 = 0; e4 < 16; ++e4) {
    float4 a = p[e4];        // kc = 0
    float4 b = p[16 + e4];   // kc = 1
    float4 c = p[32 + e4];   // kc = 2
    float4 d = p[48 + e4];   // kc = 3
    float4 bb = b4[e4];
    float g[4];
    g[0] = bb.x + a.x; g[0] += b.x; g[0] += c.x; g[0] += d.x;
    g[1] = bb.y + a.y; g[1] += b.y; g[1] += c.y; g[1] += d.y;
    g[2] = bb.z + a.z; g[2] += b.z; g[2] += c.z; g[2] += d.z;
    g[3] = bb.w + a.w; g[3] += b.w; g[3] += c.w; g[3] += d.w;
#pragma unroll
    for (int j = 0; j < 4; ++j) {
      int e = e4 * 4 + j;
      if (g[j] > m1) {
        m2 = m1; i2 = i1;
        m1 = g[j]; i1 = e;
      } else if (g[j] > m2) {
        m2 = g[j]; i2 = e;
      }
    }
  }

  float w0 = 1.0f / (1.0f + expf(m2 - m1));
  out[2 * t + 0] = w0;
  out[2 * t + 1] = 1.0f - w0;
  float* oidx = out + 2 * (size_t)M_TOKENS;
  oidx[2 * t + 0] = (float)i1;
  oidx[2 * t + 1] = (float)i2;
}

// ---------------------------------------------------------------------------
// Fallback (proven correct in round 1): fully fused, no workspace.
// ---------------------------------------------------------------------------
__global__ __launch_bounds__(64) void router_fused_kernel(
    const float* __restrict__ x, const float* __restrict__ W,
    const float* __restrict__ bias, float* __restrict__ out) {
  const int t = blockIdx.x * 64 + threadIdx.x;
  const float* xrow = x + (size_t)t * K_DIM;

  float acc[E_EXPERTS];
#pragma unroll
  for (int e = 0; e < E_EXPERTS; ++e) acc[e] = 0.0f;

  for (int k4 = 0; k4 < K_DIM; k4 += 4) {
    float4 xv = *reinterpret_cast<const float4*>(xrow + k4);
    float xs[4] = {xv.x, xv.y, xv.z, xv.w};
#pragma unroll
    for (int kk = 0; kk < 4; ++kk) {
      const float* wrow = W + (size_t)(k4 + kk) * E_EXPERTS;
#pragma unroll
      for (int e = 0; e < E_EXPERTS; ++e) acc[e] = fmaf(xs[kk], wrow[e], acc[e]);
    }
  }

  float m1 = -INFINITY, m2 = -INFINITY;
  int i1 = 0, i2 = 0;
#pragma unroll
  for (int e = 0; e < E_EXPERTS; ++e) {
    float g = acc[e] + bias[e];
    if (g > m1) {
      m2 = m1; i2 = i1;
      m1 = g; i1 = e;
    } else if (g > m2) {
      m2 = g; i2 = e;
    }
  }

  float w0 = 1.0f / (1.0f + expf(m2 - m1));
  out[2 * t + 0] = w0;
  out[2 * t + 1] = 1.0f - w0;
  float* oidx = out + 2 * (size_t)M_TOKENS;
  oidx[2 * t + 0] = (float)i1;
  oidx[2 * t + 1] = (float)i2;
}

extern "C" void kernel_launch(void* const* d_in, const int* in_sizes, int n_in,
                              void* d_out, int out_size, void* d_ws, size_t ws_size,
                              hipStream_t stream) {
  const float* x = (const float*)d_in[0];
  const float* W = (const float*)d_in[1];
  const float* b = (const float*)d_in[2];
  float* out = (float*)d_out;

  const size_t need = (size_t)M_TOKENS * PSTRIDE * sizeof(float);
  if (ws_size >= need) {
    float* part = (float*)d_ws;
    gates_kernel<<<(M_TOKENS / TT) * KSPLIT, 256, 0, stream>>>(x, W, part);
    reduce_topk_kernel<<<M_TOKENS / 64, 64, 0, stream>>>(part, b, out);
  } else {
    router_fused_kernel<<<M_TOKENS / 64, 64, 0, stream>>>(x, W, b, out);
  }
}